// Round 10
// baseline (117.526 us; speedup 1.0000x reference)
//
#include <hip/hip_runtime.h>
#include <math.h>

#define N_ROWS 4096
#define DIM    128
#define A_LAB  512
#define INV_TAU 14.285714285714286f
#define C_EXP   20.609929155556620f   // INV_TAU * log2(e)

typedef __attribute__((ext_vector_type(8))) short short8;   // 8 bf16 (4 VGPRs)
typedef __attribute__((ext_vector_type(4))) float f32x4;    // MFMA C/D frag (16x16)

// ---------------- workspace layout (bytes) ----------------
// zbf   u16 [8192*128]   @ 0          (2,097,152)  FRAG-MAJOR (see k_norm_pack)
// plab  u32 [4096*16]    @ 2,097,152  (262,144)    bit-packed labels, 64 B/row
// s     i32 [4096]       @ 4,194,304  (16,384)
// part  f32 [3*4096]     @ 4,210,688  (49,152)     atomically accumulated
// pm    u32 [4096*128]   @ 4,259,840  (2,097,152)  pos-bit mask [row][col word]

__device__ __forceinline__ unsigned short f2bf(float f) {
  unsigned int u = __builtin_bit_cast(unsigned int, f);
  u += 0x7fffu + ((u >> 16) & 1u);            // round-to-nearest-even
  return (unsigned short)(u >> 16);
}

// ------------ kernel 1: L2-normalize (-> bf16, frag-major) + labels -> BIT-packed ------------
// Labels are 0/1: pack 8 per byte.  Lane holds labels [lane*8, +8) of row r ->
// byte 'lane' of the 64-byte row (little-endian: word lane>>2, byte lane&3,
// bit t) so global bit k = lane*8+t lands at word k>>5, bit k&31.
__global__ __launch_bounds__(256) void k_norm_pack(
    const float* __restrict__ z1, const float* __restrict__ z2,
    const int* __restrict__ labels,
    unsigned int* __restrict__ zbf, unsigned char* __restrict__ plab,
    int* __restrict__ s, float* __restrict__ part, float* __restrict__ out)
{
  {
    const int idx = blockIdx.x * 256 + threadIdx.x;
    if (idx < 3 * 4096) part[idx] = 0.0f;
    if (idx == 0) out[0] = 0.0f;
  }
  const int wave = threadIdx.x >> 6, lane = threadIdx.x & 63;
  const int r = blockIdx.x * 4 + wave;         // 0..8191
  const float* src = (r < N_ROWS) ? (z1 + (size_t)r * DIM)
                                  : (z2 + (size_t)(r - N_ROWS) * DIM);
  float2 x = ((const float2*)src)[lane];
  float ss = x.x * x.x + x.y * x.y;
  #pragma unroll
  for (int off = 32; off > 0; off >>= 1) ss += __shfl_xor(ss, off);
  const float inv = 1.0f / fmaxf(sqrtf(ss), 1e-12f);
  const unsigned int lo = f2bf(x.x * inv);
  const unsigned int hi = f2bf(x.y * inv);
  {
    // row r, dword index 'lane' (bytes lane*4). unit u=lane>>2, dword p=lane&3.
    const int u = lane >> 2, p = lane & 3;
    const int kf = u >> 2, quad = u & 3;
    const int g = r >> 4;
    zbf[(size_t)(((g * 4 + kf) * 64) + ((r & 15) + (quad << 4))) * 4 + p] = (hi << 16) | lo;
  }

  if (r < N_ROWS) {
    const int4* lp = (const int4*)(labels + (size_t)r * A_LAB);
    const int4 a = lp[2 * lane], b = lp[2 * lane + 1];
    const unsigned int p8 =
        (unsigned int)(a.x != 0)        | ((unsigned int)(a.y != 0) << 1)
      | ((unsigned int)(a.z != 0) << 2) | ((unsigned int)(a.w != 0) << 3)
      | ((unsigned int)(b.x != 0) << 4) | ((unsigned int)(b.y != 0) << 5)
      | ((unsigned int)(b.z != 0) << 6) | ((unsigned int)(b.w != 0) << 7);
    plab[(size_t)r * 64 + lane] = (unsigned char)p8;
    int cnt = __popc(p8);
    #pragma unroll
    for (int off = 32; off > 0; off >>= 1) cnt += __shfl_xor(cnt, off);
    if (lane == 0) s[r] = cnt;
  }
}

// ------------ kernel 1.5: jaccard -> pos-bit mask, BIT-POPCOUNT VALU path ------------
// R3-R8 lesson: the i8-MFMA path is pinned at ~21 us by moving 512 B/row of
// byte-labels regardless of staging/occupancy.  Labels are 1-bit: packed rows
// are 64 B.  inter(i,j) = popc(AND) over 16 words = 32 VALU ops/pair ->
// ~7 us chip-wide at the VALU ceiling, with 256 KB total label traffic.
// Thread = one anchor row i (16 u32 in regs); iterates a 128-col LDS panel
// (8 KB, uniform-addr broadcast ds_reads); builds its own pm words directly
// (no ballot, no transpose, no MFMA).  Integer threshold identical to the
// absmax-0-verified form: jacc>=0.3 <=> 13*inter >= 3*(s_i+s_j).
// Grid 32x16 x 256t = 512 blocks = 2 waves/SIMD; ~40 VGPR.
__global__ __launch_bounds__(256, 2) void k_jac(
    const uint4* __restrict__ plab4, const int* __restrict__ s,
    unsigned int* __restrict__ pm)
{
  __shared__ __align__(16) uint4 cpan[128 * 4];   // 8 KB: 128 packed col rows
  __shared__ int cs[128];                          // 3*s[j] per col

  const int tid = threadIdx.x;
  const int j0 = blockIdx.x * 128;                // col range [j0, +128)
  const int i  = blockIdx.y * 256 + tid;          // this thread's anchor row

  // stage col panel: 512 uint4, coalesced (2 per thread)
  cpan[tid]       = plab4[(size_t)(j0 + (tid >> 2)) * 4 + (tid & 3)];
  cpan[256 + tid] = plab4[(size_t)(j0 + 64 + (tid >> 2)) * 4 + (tid & 3)];
  if (tid < 128) cs[tid] = 3 * s[j0 + tid];

  // own row: 16 u32 in regs
  uint4 rw0 = plab4[(size_t)i * 4 + 0];
  uint4 rw1 = plab4[(size_t)i * 4 + 1];
  uint4 rw2 = plab4[(size_t)i * 4 + 2];
  uint4 rw3 = plab4[(size_t)i * 4 + 3];
  const int s3i = 3 * s[i];

  __syncthreads();

  #pragma unroll 1
  for (int wq = 0; wq < 4; ++wq) {
    unsigned int mw = 0;
    #pragma unroll 8
    for (int jj = 0; jj < 32; ++jj) {
      const int jl = wq * 32 + jj;
      const uint4 c0 = cpan[jl * 4 + 0];
      const uint4 c1 = cpan[jl * 4 + 1];
      const uint4 c2 = cpan[jl * 4 + 2];
      const uint4 c3 = cpan[jl * 4 + 3];
      int inter = __popc(rw0.x & c0.x);
      inter += __popc(rw0.y & c0.y);
      inter += __popc(rw0.z & c0.z);
      inter += __popc(rw0.w & c0.w);
      inter += __popc(rw1.x & c1.x);
      inter += __popc(rw1.y & c1.y);
      inter += __popc(rw1.z & c1.z);
      inter += __popc(rw1.w & c1.w);
      inter += __popc(rw2.x & c2.x);
      inter += __popc(rw2.y & c2.y);
      inter += __popc(rw2.z & c2.z);
      inter += __popc(rw2.w & c2.w);
      inter += __popc(rw3.x & c3.x);
      inter += __popc(rw3.y & c3.y);
      inter += __popc(rw3.z & c3.z);
      inter += __popc(rw3.w & c3.w);
      const bool ok = 13 * inter >= s3i + cs[jl];
      mw |= ((unsigned int)ok) << jj;
    }
    pm[(size_t)i * 128 + blockIdx.x * 4 + wq] = mw;
  }
}

// ------------ kernel 2: similarity + masked-softmax (S phase only), 512 threads ------------
// EXACT R6 structure (measured-best S; R8's reg-prefetch reverted): mask words
// from pm[] (one uint4 per anchor row), B panels LDS-staged per half
// (contiguous 32 KB memcpy, conflict-free lane-contiguous ds_read_b128).
// LDS 32.8 KB -> 4 blocks/CU, 32 waves/CU at VGPR<=64.
__global__ __launch_bounds__(512, 4) void k_fused(
    const unsigned int* __restrict__ pm,
    const unsigned short* __restrict__ zbf, float* __restrict__ part)
{
  __shared__ __align__(16) char bpanel[32768];       // one half's S-phase B panel
  const int tid = threadIdx.x;
  const int ibase = blockIdx.x * 128, jbase = blockIdx.y * 128;
  const int wave = tid >> 6, lane = tid & 63;
  const bool diag = (ibase == jbase);
  const char* gz = (const char*)zbf;

  const int col = lane & 15, quad = lane >> 4;
  const int srow = wave * 16;                    // this wave: 16 anchor rows
  const int gA = (ibase + srow) >> 4;

  // mask words for this wave's rows (one uint4 per row from global pm)
  uint4 pw[4];
  #pragma unroll
  for (int reg = 0; reg < 4; ++reg)
    pw[reg] = *(const uint4*)&pm[(size_t)(ibase + srow + quad * 4 + reg) * 128 + (jbase >> 5)];

  // sim A-fragments
  short8 afr[4];
  #pragma unroll
  for (int kf = 0; kf < 4; ++kf)
    afr[kf] = *(const short8*)(gz + (size_t)((gA * 4 + kf) * 64 + lane) * 16);

  // stage half-0 B panel (cols jbase..+128 of z1n): contiguous 32 KB memcpy
  {
    const char* srcp = gz + (size_t)(jbase >> 4) * 4096;
    #pragma unroll
    for (int q = 0; q < 4; ++q)
      *(uint4*)(bpanel + (size_t)(q * 512 + tid) * 16) =
          *(const uint4*)(srcp + (size_t)(q * 512 + tid) * 16);
  }

  __syncthreads();   // half-0 panel ready

  // ---------------- phase S: similarity + softmax partials ----------------
  float lacc[4], Sacc[4], Pcnt[4];
  #pragma unroll
  for (int reg = 0; reg < 4; ++reg) { lacc[reg] = 0; Sacc[reg] = 0; Pcnt[reg] = 0; }

  #pragma unroll
  for (int half = 0; half < 2; ++half) {
    if (half == 1) {
      __syncthreads();   // all waves done reading half-0 panel
      const char* srcp = gz + (size_t)((N_ROWS + jbase) >> 4) * 4096;
      #pragma unroll
      for (int q = 0; q < 4; ++q)
        *(uint4*)(bpanel + (size_t)(q * 512 + tid) * 16) =
            *(const uint4*)(srcp + (size_t)(q * 512 + tid) * 16);
      __syncthreads();   // half-1 panel ready
    }

    f32x4 acc[8];
    #pragma unroll
    for (int nt = 0; nt < 8; ++nt) acc[nt] = (f32x4){0, 0, 0, 0};

    #pragma unroll
    for (int nt = 0; nt < 8; ++nt) {
      short8 bfr[4];
      #pragma unroll
      for (int kf = 0; kf < 4; ++kf)
        bfr[kf] = *(const short8*)(bpanel + (size_t)((nt * 4 + kf) * 64 + lane) * 16);
      #pragma unroll
      for (int kf = 0; kf < 4; ++kf)
        acc[nt] = __builtin_amdgcn_mfma_f32_16x16x32_bf16(afr[kf], bfr[kf], acc[nt], 0, 0, 0);
    }

    if (!diag) {
      // slim: same mask both halves, no self/aug; P via popcount at the end
      #pragma unroll
      for (int nt = 0; nt < 8; ++nt) {
        const int bitpos = (nt & 1) * 16 + col;
        #pragma unroll
        for (int reg = 0; reg < 4; ++reg) {
          const unsigned int w = ((const unsigned int*)&pw[reg])[nt >> 1];
          const float d = acc[nt][reg];
          lacc[reg] += exp2f(fmaf(d, C_EXP, -C_EXP));
          if ((w >> bitpos) & 1) Sacc[reg] += d;
        }
      }
    } else {
      const bool left = (half == 0);
      #pragma unroll
      for (int nt = 0; nt < 8; ++nt) {
        const int joff = nt * 16 + col;
        const int jc = jbase + joff;
        const int bitpos = joff & 31;
        #pragma unroll
        for (int reg = 0; reg < 4; ++reg) {
          const int i = ibase + srow + quad * 4 + reg;
          const unsigned int w = ((const unsigned int*)&pw[reg])[nt >> 1];
          const float d = acc[nt][reg];
          const bool bit = (w >> bitpos) & 1;
          const bool self = left && (jc == i);
          const bool pos = left ? (bit && !self) : (bit || (jc == i));
          const float e = exp2f(fmaf(d, C_EXP, -C_EXP));
          if (!self) lacc[reg] += e;
          if (pos) { Sacc[reg] += d; Pcnt[reg] += 1.0f; }
        }
      }
    }
  }

  // ---- reduce across the 16 col-lanes, atomically accumulate per-anchor ----
  #pragma unroll
  for (int reg = 0; reg < 4; ++reg) {
    float l = lacc[reg], S = Sacc[reg], P = Pcnt[reg];
    #pragma unroll
    for (int m = 1; m < 16; m <<= 1) {
      l += __shfl_xor(l, m);
      S += __shfl_xor(S, m);
      if (diag) P += __shfl_xor(P, m);
    }
    if (col == 0) {
      const int i = ibase + srow + quad * 4 + reg;
      if (!diag) {
        const uint4 w = pw[reg];
        P = 2.0f * (float)(__popc(w.x) + __popc(w.y) + __popc(w.z) + __popc(w.w));
      }
      atomicAdd(&part[i], l);
      atomicAdd(&part[4096 + i], S);
      atomicAdd(&part[8192 + i], P);
    }
  }
}

// ---------------- kernel 3: per-anchor loss + atomic final reduce ----------------
__global__ __launch_bounds__(128) void k_loss(
    const float* __restrict__ part, float* __restrict__ out)
{
  const int a = blockIdx.x * 128 + threadIdx.x;   // 0..4095
  const float l = part[a];
  const float S = part[4096 + a];
  const float P = part[8192 + a];
  const float np = fmaxf(P, 1.0f);
  float v = INV_TAU + logf(l + 1e-8f) - (S * INV_TAU) / np;
  #pragma unroll
  for (int off = 32; off > 0; off >>= 1) v += __shfl_xor(v, off);
  __shared__ float ws2[2];
  const int wave = threadIdx.x >> 6, lane = threadIdx.x & 63;
  if (lane == 0) ws2[wave] = v;
  __syncthreads();
  if (threadIdx.x == 0) atomicAdd(out, (ws2[0] + ws2[1]) * (1.0f / (float)N_ROWS));
}

extern "C" void kernel_launch(void* const* d_in, const int* in_sizes, int n_in,
                              void* d_out, int out_size, void* d_ws, size_t ws_size,
                              hipStream_t stream) {
  const float* z1 = (const float*)d_in[0];
  const float* z2 = (const float*)d_in[1];
  const int* labels = (const int*)d_in[2];
  float* out = (float*)d_out;
  char* ws = (char*)d_ws;

  unsigned int* zbf    = (unsigned int*)(ws);
  unsigned char* plab  = (unsigned char*)(ws + 2097152);
  int* s               = (int*)(ws + 4194304);
  float* part          = (float*)(ws + 4210688);
  unsigned int* pm     = (unsigned int*)(ws + 4259840);

  hipLaunchKernelGGL(k_norm_pack, dim3(2048), dim3(256), 0, stream,
                     z1, z2, labels, zbf, plab, s, part, out);
  hipLaunchKernelGGL(k_jac, dim3(32, 16), dim3(256), 0, stream,
                     (const uint4*)plab, s, pm);
  hipLaunchKernelGGL(k_fused, dim3(32, 32), dim3(512), 0, stream,
                     pm, (const unsigned short*)zbf, part);
  hipLaunchKernelGGL(k_loss, dim3(32), dim3(128), 0, stream, part, out);
}

// Round 11
// 115.028 us; speedup vs baseline: 1.0217x; 1.0217x over previous
//
#include <hip/hip_runtime.h>
#include <math.h>

#define N_ROWS 4096
#define DIM    128
#define A_LAB  512
#define INV_TAU 14.285714285714286f
#define C_EXP   20.609929155556620f   // INV_TAU * log2(e)

typedef __attribute__((ext_vector_type(8))) short short8;   // 8 bf16 (4 VGPRs)
typedef __attribute__((ext_vector_type(4))) float f32x4;    // MFMA C/D frag (16x16)

// ---------------- workspace layout (bytes) ----------------
// zbf   u16 [8192*128]   @ 0          (2,097,152)  FRAG-MAJOR (see k_norm_pack)
// plab  u32 [4096*16]    @ 2,097,152  (262,144)    bit-packed labels, 64 B/row
// s     i32 [4096]       @ 4,194,304  (16,384)
// part  f32 [3*4096]     @ 4,210,688  (49,152)     atomically accumulated
// pm    u32 [4096*128]   @ 4,259,840  (2,097,152)  pos-bit mask [row][col word]

__device__ __forceinline__ unsigned short f2bf(float f) {
  unsigned int u = __builtin_bit_cast(unsigned int, f);
  u += 0x7fffu + ((u >> 16) & 1u);            // round-to-nearest-even
  return (unsigned short)(u >> 16);
}

// ------------ kernel 1: L2-normalize (-> bf16, frag-major) + labels -> BIT-packed ------------
// Labels are 0/1: pack 8 per byte; popc(AND) is bit-order-invariant so the
// exact bit placement only needs to be consistent row-to-row.
__global__ __launch_bounds__(256) void k_norm_pack(
    const float* __restrict__ z1, const float* __restrict__ z2,
    const int* __restrict__ labels,
    unsigned int* __restrict__ zbf, unsigned char* __restrict__ plab,
    int* __restrict__ s, float* __restrict__ part, float* __restrict__ out)
{
  {
    const int idx = blockIdx.x * 256 + threadIdx.x;
    if (idx < 3 * 4096) part[idx] = 0.0f;
    if (idx == 0) out[0] = 0.0f;
  }
  const int wave = threadIdx.x >> 6, lane = threadIdx.x & 63;
  const int r = blockIdx.x * 4 + wave;         // 0..8191
  const float* src = (r < N_ROWS) ? (z1 + (size_t)r * DIM)
                                  : (z2 + (size_t)(r - N_ROWS) * DIM);
  float2 x = ((const float2*)src)[lane];
  float ss = x.x * x.x + x.y * x.y;
  #pragma unroll
  for (int off = 32; off > 0; off >>= 1) ss += __shfl_xor(ss, off);
  const float inv = 1.0f / fmaxf(sqrtf(ss), 1e-12f);
  const unsigned int lo = f2bf(x.x * inv);
  const unsigned int hi = f2bf(x.y * inv);
  {
    // row r, dword index 'lane' (bytes lane*4). unit u=lane>>2, dword p=lane&3.
    const int u = lane >> 2, p = lane & 3;
    const int kf = u >> 2, quad = u & 3;
    const int g = r >> 4;
    zbf[(size_t)(((g * 4 + kf) * 64) + ((r & 15) + (quad << 4))) * 4 + p] = (hi << 16) | lo;
  }

  if (r < N_ROWS) {
    const int4* lp = (const int4*)(labels + (size_t)r * A_LAB);
    const int4 a = lp[2 * lane], b = lp[2 * lane + 1];
    const unsigned int p8 =
        (unsigned int)(a.x != 0)        | ((unsigned int)(a.y != 0) << 1)
      | ((unsigned int)(a.z != 0) << 2) | ((unsigned int)(a.w != 0) << 3)
      | ((unsigned int)(b.x != 0) << 4) | ((unsigned int)(b.y != 0) << 5)
      | ((unsigned int)(b.z != 0) << 6) | ((unsigned int)(b.w != 0) << 7);
    plab[(size_t)r * 64 + lane] = (unsigned char)p8;
    int cnt = __popc(p8);
    #pragma unroll
    for (int off = 32; off > 0; off >>= 1) cnt += __shfl_xor(cnt, off);
    if (lane == 0) s[r] = cnt;
  }
}

// ------------ kernel 1.5: jaccard -> pos-bit mask, bit-popcount, 4 rows/thread ------------
// R10 lesson: v1 (1 row/thread) was LDS-PIPE bound, not VALU bound — a
// broadcast ds_read_b128 still costs its ~12cy throughput slot, and each
// thread streamed the whole panel: 4096 reads/CU ~ 20 us.  LDS instruction
// count scales as 1/(rows per thread): R=4 -> ~5 us, under the ~7.3 us VALU
// floor (16.8M pairs x 34 ops / 64 lanes / 1024 SIMDs).  Col-tile shrinks to
// 32 (2 KB panel) to keep 512 blocks = 2/CU = 8 waves/CU.  One col-tile ==
// one pm word: each thread builds mw[4] in regs, 4 direct stores (no ballot,
// no transpose).  Threshold integer form unchanged (absmax-0 since R0):
// jacc>=0.3 <=> 13*inter >= 3*(s_i+s_j).  ~100 VGPR, statically indexed.
__global__ __launch_bounds__(256, 2) void k_jac(
    const uint4* __restrict__ plab4, const int* __restrict__ s,
    unsigned int* __restrict__ pm)
{
  __shared__ __align__(16) uint4 cpan[32 * 4];     // 2 KB: 32 packed col rows
  __shared__ int cs[32];                           // 3*s[j] per col

  const int tid = threadIdx.x;
  const int cx = blockIdx.x;                 // col word 0..127 -> cols [cx*32,+32)
  const int i0 = blockIdx.y * 1024 + tid;    // this thread's rows: i0 + 256*r

  if (tid < 128) cpan[tid] = plab4[(size_t)(cx * 32 + (tid >> 2)) * 4 + (tid & 3)];
  if (tid < 32)  cs[tid] = 3 * s[cx * 32 + tid];

  // own 4 rows: 64 u32 in regs (static indexing only)
  uint4 rw[4][4];
  int s3i[4];
  #pragma unroll
  for (int r = 0; r < 4; ++r) {
    const int i = i0 + 256 * r;
    #pragma unroll
    for (int q = 0; q < 4; ++q) rw[r][q] = plab4[(size_t)i * 4 + q];
    s3i[r] = 3 * s[i];
  }

  __syncthreads();

  unsigned int mw0 = 0, mw1 = 0, mw2 = 0, mw3 = 0;
  #pragma unroll 4
  for (int jl = 0; jl < 32; ++jl) {
    const uint4 c0 = cpan[jl * 4 + 0];
    const uint4 c1 = cpan[jl * 4 + 1];
    const uint4 c2 = cpan[jl * 4 + 2];
    const uint4 c3 = cpan[jl * 4 + 3];
    const int thr = cs[jl];
    #pragma unroll
    for (int r = 0; r < 4; ++r) {
      int inter = __popc(rw[r][0].x & c0.x);
      inter += __popc(rw[r][0].y & c0.y);
      inter += __popc(rw[r][0].z & c0.z);
      inter += __popc(rw[r][0].w & c0.w);
      inter += __popc(rw[r][1].x & c1.x);
      inter += __popc(rw[r][1].y & c1.y);
      inter += __popc(rw[r][1].z & c1.z);
      inter += __popc(rw[r][1].w & c1.w);
      inter += __popc(rw[r][2].x & c2.x);
      inter += __popc(rw[r][2].y & c2.y);
      inter += __popc(rw[r][2].z & c2.z);
      inter += __popc(rw[r][2].w & c2.w);
      inter += __popc(rw[r][3].x & c3.x);
      inter += __popc(rw[r][3].y & c3.y);
      inter += __popc(rw[r][3].z & c3.z);
      inter += __popc(rw[r][3].w & c3.w);
      const unsigned int ok = (unsigned int)(13 * inter >= s3i[r] + thr) << jl;
      if (r == 0) mw0 |= ok;
      else if (r == 1) mw1 |= ok;
      else if (r == 2) mw2 |= ok;
      else mw3 |= ok;
    }
  }
  pm[(size_t)(i0)        * 128 + cx] = mw0;
  pm[(size_t)(i0 + 256)  * 128 + cx] = mw1;
  pm[(size_t)(i0 + 512)  * 128 + cx] = mw2;
  pm[(size_t)(i0 + 768)  * 128 + cx] = mw3;
}

// ------------ kernel 2: similarity + masked-softmax (S phase only), 512 threads ------------
// EXACT R6 structure (measured-best S): mask words from pm[] (one uint4 per
// anchor row), B panels LDS-staged per half (contiguous 32 KB memcpy,
// conflict-free lane-contiguous ds_read_b128).  LDS 32.8 KB -> 4 blocks/CU.
__global__ __launch_bounds__(512, 4) void k_fused(
    const unsigned int* __restrict__ pm,
    const unsigned short* __restrict__ zbf, float* __restrict__ part)
{
  __shared__ __align__(16) char bpanel[32768];       // one half's S-phase B panel
  const int tid = threadIdx.x;
  const int ibase = blockIdx.x * 128, jbase = blockIdx.y * 128;
  const int wave = tid >> 6, lane = tid & 63;
  const bool diag = (ibase == jbase);
  const char* gz = (const char*)zbf;

  const int col = lane & 15, quad = lane >> 4;
  const int srow = wave * 16;                    // this wave: 16 anchor rows
  const int gA = (ibase + srow) >> 4;

  // mask words for this wave's rows (one uint4 per row from global pm)
  uint4 pw[4];
  #pragma unroll
  for (int reg = 0; reg < 4; ++reg)
    pw[reg] = *(const uint4*)&pm[(size_t)(ibase + srow + quad * 4 + reg) * 128 + (jbase >> 5)];

  // sim A-fragments
  short8 afr[4];
  #pragma unroll
  for (int kf = 0; kf < 4; ++kf)
    afr[kf] = *(const short8*)(gz + (size_t)((gA * 4 + kf) * 64 + lane) * 16);

  // stage half-0 B panel (cols jbase..+128 of z1n): contiguous 32 KB memcpy
  {
    const char* srcp = gz + (size_t)(jbase >> 4) * 4096;
    #pragma unroll
    for (int q = 0; q < 4; ++q)
      *(uint4*)(bpanel + (size_t)(q * 512 + tid) * 16) =
          *(const uint4*)(srcp + (size_t)(q * 512 + tid) * 16);
  }

  __syncthreads();   // half-0 panel ready

  // ---------------- phase S: similarity + softmax partials ----------------
  float lacc[4], Sacc[4], Pcnt[4];
  #pragma unroll
  for (int reg = 0; reg < 4; ++reg) { lacc[reg] = 0; Sacc[reg] = 0; Pcnt[reg] = 0; }

  #pragma unroll
  for (int half = 0; half < 2; ++half) {
    if (half == 1) {
      __syncthreads();   // all waves done reading half-0 panel
      const char* srcp = gz + (size_t)((N_ROWS + jbase) >> 4) * 4096;
      #pragma unroll
      for (int q = 0; q < 4; ++q)
        *(uint4*)(bpanel + (size_t)(q * 512 + tid) * 16) =
            *(const uint4*)(srcp + (size_t)(q * 512 + tid) * 16);
      __syncthreads();   // half-1 panel ready
    }

    f32x4 acc[8];
    #pragma unroll
    for (int nt = 0; nt < 8; ++nt) acc[nt] = (f32x4){0, 0, 0, 0};

    #pragma unroll
    for (int nt = 0; nt < 8; ++nt) {
      short8 bfr[4];
      #pragma unroll
      for (int kf = 0; kf < 4; ++kf)
        bfr[kf] = *(const short8*)(bpanel + (size_t)((nt * 4 + kf) * 64 + lane) * 16);
      #pragma unroll
      for (int kf = 0; kf < 4; ++kf)
        acc[nt] = __builtin_amdgcn_mfma_f32_16x16x32_bf16(afr[kf], bfr[kf], acc[nt], 0, 0, 0);
    }

    if (!diag) {
      // slim: same mask both halves, no self/aug; P via popcount at the end
      #pragma unroll
      for (int nt = 0; nt < 8; ++nt) {
        const int bitpos = (nt & 1) * 16 + col;
        #pragma unroll
        for (int reg = 0; reg < 4; ++reg) {
          const unsigned int w = ((const unsigned int*)&pw[reg])[nt >> 1];
          const float d = acc[nt][reg];
          lacc[reg] += exp2f(fmaf(d, C_EXP, -C_EXP));
          if ((w >> bitpos) & 1) Sacc[reg] += d;
        }
      }
    } else {
      const bool left = (half == 0);
      #pragma unroll
      for (int nt = 0; nt < 8; ++nt) {
        const int joff = nt * 16 + col;
        const int jc = jbase + joff;
        const int bitpos = joff & 31;
        #pragma unroll
        for (int reg = 0; reg < 4; ++reg) {
          const int i = ibase + srow + quad * 4 + reg;
          const unsigned int w = ((const unsigned int*)&pw[reg])[nt >> 1];
          const float d = acc[nt][reg];
          const bool bit = (w >> bitpos) & 1;
          const bool self = left && (jc == i);
          const bool pos = left ? (bit && !self) : (bit || (jc == i));
          const float e = exp2f(fmaf(d, C_EXP, -C_EXP));
          if (!self) lacc[reg] += e;
          if (pos) { Sacc[reg] += d; Pcnt[reg] += 1.0f; }
        }
      }
    }
  }

  // ---- reduce across the 16 col-lanes, atomically accumulate per-anchor ----
  #pragma unroll
  for (int reg = 0; reg < 4; ++reg) {
    float l = lacc[reg], S = Sacc[reg], P = Pcnt[reg];
    #pragma unroll
    for (int m = 1; m < 16; m <<= 1) {
      l += __shfl_xor(l, m);
      S += __shfl_xor(S, m);
      if (diag) P += __shfl_xor(P, m);
    }
    if (col == 0) {
      const int i = ibase + srow + quad * 4 + reg;
      if (!diag) {
        const uint4 w = pw[reg];
        P = 2.0f * (float)(__popc(w.x) + __popc(w.y) + __popc(w.z) + __popc(w.w));
      }
      atomicAdd(&part[i], l);
      atomicAdd(&part[4096 + i], S);
      atomicAdd(&part[8192 + i], P);
    }
  }
}

// ---------------- kernel 3: per-anchor loss + atomic final reduce ----------------
__global__ __launch_bounds__(128) void k_loss(
    const float* __restrict__ part, float* __restrict__ out)
{
  const int a = blockIdx.x * 128 + threadIdx.x;   // 0..4095
  const float l = part[a];
  const float S = part[4096 + a];
  const float P = part[8192 + a];
  const float np = fmaxf(P, 1.0f);
  float v = INV_TAU + logf(l + 1e-8f) - (S * INV_TAU) / np;
  #pragma unroll
  for (int off = 32; off > 0; off >>= 1) v += __shfl_xor(v, off);
  __shared__ float ws2[2];
  const int wave = threadIdx.x >> 6, lane = threadIdx.x & 63;
  if (lane == 0) ws2[wave] = v;
  __syncthreads();
  if (threadIdx.x == 0) atomicAdd(out, (ws2[0] + ws2[1]) * (1.0f / (float)N_ROWS));
}

extern "C" void kernel_launch(void* const* d_in, const int* in_sizes, int n_in,
                              void* d_out, int out_size, void* d_ws, size_t ws_size,
                              hipStream_t stream) {
  const float* z1 = (const float*)d_in[0];
  const float* z2 = (const float*)d_in[1];
  const int* labels = (const int*)d_in[2];
  float* out = (float*)d_out;
  char* ws = (char*)d_ws;

  unsigned int* zbf    = (unsigned int*)(ws);
  unsigned char* plab  = (unsigned char*)(ws + 2097152);
  int* s               = (int*)(ws + 4194304);
  float* part          = (float*)(ws + 4210688);
  unsigned int* pm     = (unsigned int*)(ws + 4259840);

  hipLaunchKernelGGL(k_norm_pack, dim3(2048), dim3(256), 0, stream,
                     z1, z2, labels, zbf, plab, s, part, out);
  hipLaunchKernelGGL(k_jac, dim3(128, 4), dim3(256), 0, stream,
                     (const uint4*)plab, s, pm);
  hipLaunchKernelGGL(k_fused, dim3(32, 32), dim3(512), 0, stream,
                     pm, (const unsigned short*)zbf, part);
  hipLaunchKernelGGL(k_loss, dim3(32), dim3(128), 0, stream, part, out);
}

// Round 12
// 103.281 us; speedup vs baseline: 1.1379x; 1.1137x over previous
//
#include <hip/hip_runtime.h>
#include <math.h>

#define N_ROWS 4096
#define DIM    128
#define A_LAB  512
#define INV_TAU 14.285714285714286f
#define C_EXP   20.609929155556620f   // INV_TAU * log2(e)

typedef __attribute__((ext_vector_type(8))) short short8;   // 8 bf16 (4 VGPRs)
typedef __attribute__((ext_vector_type(4))) float f32x4;    // MFMA C/D frag (16x16)
typedef __attribute__((ext_vector_type(4))) int i32x4;      // i8 MFMA A/B frag
typedef __attribute__((ext_vector_type(16))) int i32x16;    // i8 MFMA C/D frag (32x32)

// ---------------- workspace layout (bytes) ----------------
// zbf   u16 [8192*128]   @ 0          (2,097,152)  FRAG-MAJOR (see k_norm_pack)
// labs8 i8  [4096*512]   @ 2,097,152  (2,097,152)  FRAG-MAJOR (see k_norm_pack)
// s     i32 [4096]       @ 4,194,304  (16,384)
// part  f32 [3*4096]     @ 4,210,688  (49,152)     atomically accumulated

__device__ __forceinline__ unsigned short f2bf(float f) {
  unsigned int u = __builtin_bit_cast(unsigned int, f);
  u += 0x7fffu + ((u >> 16) & 1u);            // round-to-nearest-even
  return (unsigned short)(u >> 16);
}

// ------------ kernel 1: L2-normalize (-> bf16, frag-major) + labels -> i8 frag-major ------------
__global__ __launch_bounds__(256) void k_norm_pack(
    const float* __restrict__ z1, const float* __restrict__ z2,
    const int* __restrict__ labels,
    unsigned int* __restrict__ zbf, uint2* __restrict__ labs8,
    int* __restrict__ s, float* __restrict__ part, float* __restrict__ out)
{
  {
    const int idx = blockIdx.x * 256 + threadIdx.x;
    if (idx < 3 * 4096) part[idx] = 0.0f;
    if (idx == 0) out[0] = 0.0f;
  }
  const int wave = threadIdx.x >> 6, lane = threadIdx.x & 63;
  const int r = blockIdx.x * 4 + wave;         // 0..8191
  const float* src = (r < N_ROWS) ? (z1 + (size_t)r * DIM)
                                  : (z2 + (size_t)(r - N_ROWS) * DIM);
  float2 x = ((const float2*)src)[lane];
  float ss = x.x * x.x + x.y * x.y;
  #pragma unroll
  for (int off = 32; off > 0; off >>= 1) ss += __shfl_xor(ss, off);
  const float inv = 1.0f / fmaxf(sqrtf(ss), 1e-12f);
  const unsigned int lo = f2bf(x.x * inv);
  const unsigned int hi = f2bf(x.y * inv);
  {
    // row r, dword index 'lane' (bytes lane*4). unit u=lane>>2, dword p=lane&3.
    const int u = lane >> 2, p = lane & 3;
    const int kf = u >> 2, quad = u & 3;
    const int g = r >> 4;
    zbf[(size_t)(((g * 4 + kf) * 64) + ((r & 15) + (quad << 4))) * 4 + p] = (hi << 16) | lo;
  }

  if (r < N_ROWS) {
    const int4* lp = (const int4*)(labels + (size_t)r * A_LAB);
    const int4 a = lp[2 * lane], b = lp[2 * lane + 1];
    const unsigned int w0 = (unsigned int)(a.x != 0)       | ((unsigned int)(a.y != 0) << 8)
                          | ((unsigned int)(a.z != 0) << 16) | ((unsigned int)(a.w != 0) << 24);
    const unsigned int w1 = (unsigned int)(b.x != 0)       | ((unsigned int)(b.y != 0) << 8)
                          | ((unsigned int)(b.z != 0) << 16) | ((unsigned int)(b.w != 0) << 24);
    uint2 v; v.x = w0; v.y = w1;
    // row r, bytes lane*8..+8: unit ul=lane>>1, half hp=lane&1; ks=ul>>1, h=ul&1
    const int ul = lane >> 1, hp = lane & 1;
    const int ks = ul >> 1, h = ul & 1;
    const int g = r >> 5;
    labs8[(size_t)(((g * 16 + ks) * 64) + ((r & 31) + (h << 5))) * 2 + hp] = v;
    int cnt = __popc(w0) + __popc(w1);         // bytes are 0/1 -> popc == byte sum
    #pragma unroll
    for (int off = 32; off > 0; off >>= 1) cnt += __shfl_xor(cnt, off);
    if (lane == 0) s[r] = cnt;
  }
}

// ------------ kernel 2: FUSED jaccard + sim + masked-softmax, 512 threads ------------
// EXACT R2 structure (best measured: 104.33 us total) + ONE change (T14):
// the half-0 B-panel global loads are issued at the TOP of the kernel (before
// phase J, ~3000 cy of compute to hide the ~500 cy L2 latency); only the
// ds_writes happen after the J epilogue, right before the barrier.
// R3-R11 lesson: splitting J into its own kernel never beat this fused form —
// the fused version overlaps J's load latency with S's MFMA across the 4
// resident blocks/CU.  LDS 32.8 KB -> 4 blocks/CU.
__global__ __launch_bounds__(512, 4) void k_fused(
    const unsigned char* __restrict__ labs8, const int* __restrict__ s,
    const unsigned short* __restrict__ zbf, float* __restrict__ part)
{
  __shared__ unsigned int pmL[128 * 4];              // pos-bits: [local row][col word]
  __shared__ __align__(16) char bpanel[32768];       // one half's S-phase B panel
  const int tid = threadIdx.x;
  const int ibase = blockIdx.x * 128, jbase = blockIdx.y * 128;
  const int wave = tid >> 6, lane = tid & 63;
  const bool diag = (ibase == jbase);
  const char* gl = (const char*)labs8;
  const char* gz = (const char*)zbf;

  // ---- T14 stage-split: issue half-0 B-panel loads NOW (drain during J) ----
  uint4 pf0[4];
  {
    const char* srcp = gz + (size_t)(jbase >> 4) * 4096;
    #pragma unroll
    for (int q = 0; q < 4; ++q)
      pf0[q] = *(const uint4*)(srcp + (size_t)(q * 512 + tid) * 16);
  }

  // ---------------- phase J: jaccard (frag-major direct loads) ----------------
  const int jwr = (wave >> 2) * 64;           // rows: waves 0-3 -> 0, 4-7 -> 64
  const int jwc = (wave & 3) * 32;            // cols: 32-wide slice per wave
  const int col32 = lane & 31, h = lane >> 5;

  const int s3i = 3 * s[ibase + jwr + lane];        // this wave's 64 rows
  const int s3j = 3 * s[jbase + jwc + col32];       // this lane's col

  i32x16 jacc[2];
  #pragma unroll
  for (int rt = 0; rt < 2; ++rt)
    #pragma unroll
    for (int e = 0; e < 16; ++e) jacc[rt][e] = 0;

  const int gI = (ibase + jwr) >> 5;          // two 32-row groups: gI, gI+1
  const int gJ = (jbase + jwc) >> 5;          // one 32-row group
  #pragma unroll
  for (int ks = 0; ks < 16; ++ks) {
    i32x4 a[2], b;
    #pragma unroll
    for (int rt = 0; rt < 2; ++rt)
      a[rt] = *(const i32x4*)(gl + (size_t)(((gI + rt) * 16 + ks) * 64 + lane) * 16);
    b = *(const i32x4*)(gl + (size_t)((gJ * 16 + ks) * 64 + lane) * 16);
    #pragma unroll
    for (int rt = 0; rt < 2; ++rt)
      jacc[rt] = __builtin_amdgcn_mfma_i32_32x32x32_i8(a[rt], b, jacc[rt], 0, 0, 0);
  }

  // jac epilogue: threshold + ballot -> pmL (each wave owns 64 rows x 1 word)
  const int wl = wave & 3;
  #pragma unroll
  for (int rt = 0; rt < 2; ++rt)
    #pragma unroll
    for (int reg = 0; reg < 16; ++reg) {
      const int r0 = (reg & 3) + 8 * (reg >> 2);
      const int si = __shfl(s3i, rt * 32 + r0 + 4 * h);
      const bool pred = 13 * jacc[rt][reg] >= si + s3j;
      const unsigned long long bal = __ballot(pred);
      const int lr = jwr + rt * 32 + r0;
      if (lane == 0)      pmL[lr * 4 + wl]       = (unsigned int)bal;
      else if (lane == 1) pmL[(lr + 4) * 4 + wl] = (unsigned int)(bal >> 32);
    }

  // sim A-fragments (issued before the barrier; independent of pmL)
  const int col = lane & 15, quad = lane >> 4;
  const int srow = wave * 16;                    // this wave: 16 anchor rows
  const int gA = (ibase + srow) >> 4;
  short8 afr[4];
  #pragma unroll
  for (int kf = 0; kf < 4; ++kf)
    afr[kf] = *(const short8*)(gz + (size_t)((gA * 4 + kf) * 64 + lane) * 16);

  // half-0 panel: write the prefetched registers to LDS (loads long drained)
  #pragma unroll
  for (int q = 0; q < 4; ++q)
    *(uint4*)(bpanel + (size_t)(q * 512 + tid) * 16) = pf0[q];

  __syncthreads();   // pmL visible + half-0 panel ready

  // mask words for this wave's rows (held in regs across both halves)
  uint4 pw[4];
  #pragma unroll
  for (int reg = 0; reg < 4; ++reg)
    pw[reg] = *(const uint4*)&pmL[(srow + quad * 4 + reg) * 4];

  // ---------------- phase S: similarity + softmax partials ----------------
  float lacc[4], Sacc[4], Pcnt[4];
  #pragma unroll
  for (int reg = 0; reg < 4; ++reg) { lacc[reg] = 0; Sacc[reg] = 0; Pcnt[reg] = 0; }

  #pragma unroll
  for (int half = 0; half < 2; ++half) {
    if (half == 1) {
      __syncthreads();   // all waves done reading half-0 panel
      const char* srcp = gz + (size_t)((N_ROWS + jbase) >> 4) * 4096;
      #pragma unroll
      for (int q = 0; q < 4; ++q)
        *(uint4*)(bpanel + (size_t)(q * 512 + tid) * 16) =
            *(const uint4*)(srcp + (size_t)(q * 512 + tid) * 16);
      __syncthreads();   // half-1 panel ready
    }

    f32x4 acc[8];
    #pragma unroll
    for (int nt = 0; nt < 8; ++nt) acc[nt] = (f32x4){0, 0, 0, 0};

    #pragma unroll
    for (int nt = 0; nt < 8; ++nt) {
      short8 bfr[4];
      #pragma unroll
      for (int kf = 0; kf < 4; ++kf)
        bfr[kf] = *(const short8*)(bpanel + (size_t)((nt * 4 + kf) * 64 + lane) * 16);
      #pragma unroll
      for (int kf = 0; kf < 4; ++kf)
        acc[nt] = __builtin_amdgcn_mfma_f32_16x16x32_bf16(afr[kf], bfr[kf], acc[nt], 0, 0, 0);
    }

    if (!diag) {
      // slim: same mask both halves, no self/aug; P via popcount at the end
      #pragma unroll
      for (int nt = 0; nt < 8; ++nt) {
        const int bitpos = (nt & 1) * 16 + col;
        #pragma unroll
        for (int reg = 0; reg < 4; ++reg) {
          const unsigned int w = ((const unsigned int*)&pw[reg])[nt >> 1];
          const float d = acc[nt][reg];
          lacc[reg] += exp2f(fmaf(d, C_EXP, -C_EXP));
          if ((w >> bitpos) & 1) Sacc[reg] += d;
        }
      }
    } else {
      const bool left = (half == 0);
      #pragma unroll
      for (int nt = 0; nt < 8; ++nt) {
        const int joff = nt * 16 + col;
        const int jc = jbase + joff;
        const int bitpos = joff & 31;
        #pragma unroll
        for (int reg = 0; reg < 4; ++reg) {
          const int i = ibase + srow + quad * 4 + reg;
          const unsigned int w = ((const unsigned int*)&pw[reg])[nt >> 1];
          const float d = acc[nt][reg];
          const bool bit = (w >> bitpos) & 1;
          const bool self = left && (jc == i);
          const bool pos = left ? (bit && !self) : (bit || (jc == i));
          const float e = exp2f(fmaf(d, C_EXP, -C_EXP));
          if (!self) lacc[reg] += e;
          if (pos) { Sacc[reg] += d; Pcnt[reg] += 1.0f; }
        }
      }
    }
  }

  // ---- reduce across the 16 col-lanes, atomically accumulate per-anchor ----
  #pragma unroll
  for (int reg = 0; reg < 4; ++reg) {
    float l = lacc[reg], S = Sacc[reg], P = Pcnt[reg];
    #pragma unroll
    for (int m = 1; m < 16; m <<= 1) {
      l += __shfl_xor(l, m);
      S += __shfl_xor(S, m);
      if (diag) P += __shfl_xor(P, m);
    }
    if (col == 0) {
      const int li = srow + quad * 4 + reg;
      const int i = ibase + li;
      if (!diag) {
        const uint4 w = pw[reg];
        P = 2.0f * (float)(__popc(w.x) + __popc(w.y) + __popc(w.z) + __popc(w.w));
      }
      atomicAdd(&part[i], l);
      atomicAdd(&part[4096 + i], S);
      atomicAdd(&part[8192 + i], P);
    }
  }
}

// ---------------- kernel 3: per-anchor loss + atomic final reduce ----------------
__global__ __launch_bounds__(128) void k_loss(
    const float* __restrict__ part, float* __restrict__ out)
{
  const int a = blockIdx.x * 128 + threadIdx.x;   // 0..4095
  const float l = part[a];
  const float S = part[4096 + a];
  const float P = part[8192 + a];
  const float np = fmaxf(P, 1.0f);
  float v = INV_TAU + logf(l + 1e-8f) - (S * INV_TAU) / np;
  #pragma unroll
  for (int off = 32; off > 0; off >>= 1) v += __shfl_xor(v, off);
  __shared__ float ws2[2];
  const int wave = threadIdx.x >> 6, lane = threadIdx.x & 63;
  if (lane == 0) ws2[wave] = v;
  __syncthreads();
  if (threadIdx.x == 0) atomicAdd(out, (ws2[0] + ws2[1]) * (1.0f / (float)N_ROWS));
}

extern "C" void kernel_launch(void* const* d_in, const int* in_sizes, int n_in,
                              void* d_out, int out_size, void* d_ws, size_t ws_size,
                              hipStream_t stream) {
  const float* z1 = (const float*)d_in[0];
  const float* z2 = (const float*)d_in[1];
  const int* labels = (const int*)d_in[2];
  float* out = (float*)d_out;
  char* ws = (char*)d_ws;

  unsigned int* zbf    = (unsigned int*)(ws);
  uint2* labs8         = (uint2*)(ws + 2097152);
  int* s               = (int*)(ws + 4194304);
  float* part          = (float*)(ws + 4210688);

  hipLaunchKernelGGL(k_norm_pack, dim3(2048), dim3(256), 0, stream,
                     z1, z2, labels, zbf, labs8, s, part, out);
  hipLaunchKernelGGL(k_fused, dim3(32, 32), dim3(512), 0, stream,
                     (const unsigned char*)labs8, s, (const unsigned short*)zbf, part);
  hipLaunchKernelGGL(k_loss, dim3(32), dim3(128), 0, stream, part, out);
}